// Round 16
// baseline (89.855 us; speedup 1.0000x reference)
//
#include <hip/hip_runtime.h>

typedef __bf16 bf16;
typedef __attribute__((ext_vector_type(4))) __bf16 bf16x4;
typedef __attribute__((ext_vector_type(8))) __bf16 bf16x8;
typedef __attribute__((ext_vector_type(4))) float f32x4;
typedef unsigned int u32;

#define MFMA16(a, b, c) __builtin_amdgcn_mfma_f32_16x16x32_bf16((a), (b), (c), 0, 0, 0)
#define LOG2E 1.4426950408889634f

// KV chunk, per (b, kt=0..7): 81920 bytes =
//  [0,16384): K packed in FRAGMENT order: for mfma qt (0..7), half h (0..1),
//     lane L=(u<<4)|l16, elem j: byte = qt<<11 | h<<10 | L<<4 | j<<1 holds
//     K[row R(qt,l16)][o=32h+8u+j], R = 8((l16>>2)&3)... i.e. attn lane L
//     loading qt<<11 (+1024) + L<<4 gets its S A-frag directly (L1-shared
//     across all 4 waves).
//  [16384,81920): V packed for direct wave-frag loads (R12): octet (c, mm)
//     at 16384 + (c>>6)<<14 + (mm>>2)<<12 + ((c>>4)&3)<<10 + (mm&3)<<8 +
//     (c&15)<<4. Wave w: load k at (w<<14)+(k<<10)+(lane<<4) == A-frag
//     (c=64w+16ct+l16, octet mm=4kb+u), k=4kb+ct.

// ---------------------------------------------------------------------------
// Kernel 1: fused V-pack + W prep (R12 verbatim).
// ---------------------------------------------------------------------------
__global__ __launch_bounds__(256) void vprep_kernel(const float* __restrict__ kf,
                                                    const float* __restrict__ Wq,
                                                    const float* __restrict__ Wk,
                                                    const int* __restrict__ flag,
                                                    bf16* __restrict__ KV,
                                                    bf16* __restrict__ Wbh,
                                                    bf16* __restrict__ Wbl) {
  const int bid = blockIdx.x, t = threadIdx.x;
  if (bid < 4096) {
    int i = (bid << 8) + t;  // (b, c, q8)
    int q8 = i & 127, c = (i >> 7) & 255, b = i >> 15;
    const float* src = kf + ((size_t)(((b << 8) + c)) << 10) + (q8 << 3);
    float4 f0 = *(const float4*)src;
    float4 f1 = *(const float4*)(src + 4);
    bf16x8 v;
    v[0] = (bf16)f0.x; v[1] = (bf16)f0.y; v[2] = (bf16)f0.z; v[3] = (bf16)f0.w;
    v[4] = (bf16)f1.x; v[5] = (bf16)f1.y; v[6] = (bf16)f1.z; v[7] = (bf16)f1.w;
    int kt = q8 >> 4, mm = q8 & 15;
    char* dst = (char*)KV + (size_t)((b << 3) + kt) * 81920 + 16384 +
                ((c >> 6) << 14) + ((mm >> 2) << 12) + (((c >> 4) & 3) << 10) +
                ((mm & 3) << 8) + ((c & 15) << 4);
    *(bf16x8*)dst = v;
  } else {
    int bx = bid - 4096;  // 0..31
    int z = bx >> 4;
    const float* src = (z == 0) ? Wq : ((flag[0] != 0) ? Wq : Wk);
    const float sc = (z == 0) ? LOG2E : 1.0f;  // exp2-domain softmax
    int i = ((((bx & 15) << 8) + t) << 2);
    float4 vv = *(const float4*)(src + i);
    vv.x *= sc; vv.y *= sc; vv.z *= sc; vv.w *= sc;
    bf16x4 hi, lo;
    hi[0] = (bf16)vv.x; lo[0] = (bf16)(vv.x - (float)hi[0]);
    hi[1] = (bf16)vv.y; lo[1] = (bf16)(vv.y - (float)hi[1]);
    hi[2] = (bf16)vv.z; lo[2] = (bf16)(vv.z - (float)hi[2]);
    hi[3] = (bf16)vv.w; lo[3] = (bf16)(vv.w - (float)hi[3]);
    *(bf16x4*)(Wbh + (z << 14) + i) = hi;
    *(bf16x4*)(Wbl + (z << 14) + i) = lo;
  }
}

// ---------------------------------------------------------------------------
// Kernel 2: MFMA projection. z=0 -> Qp (log2e-scaled, reads qf fp32);
// z=1 -> KV K-part in FRAGMENT-packed order. z=1 B-frags read bf16 from the
// packed KV V-region (bit-identical to own cvt).
// ---------------------------------------------------------------------------
__global__ __launch_bounds__(256) void proj_kernel(const float* __restrict__ qf,
                                                   const bf16* __restrict__ Wbh,
                                                   const bf16* __restrict__ Wbl,
                                                   const float* __restrict__ bq,
                                                   const float* __restrict__ bk,
                                                   const int* __restrict__ flag,
                                                   bf16* __restrict__ Qp,
                                                   bf16* __restrict__ KV) {
  const int b = blockIdx.y, z = blockIdx.z;
  const bf16* Wh = Wbh + z * 16384;
  const bf16* Wl = Wbl + z * 16384;
  const float* bias = z ? (flag[0] ? bq : bk) : bq;

  const int t = threadIdx.x;
  const int w = t >> 6, lane = t & 63;
  const int g = lane >> 4, l16 = lane & 15;
  const int wo = w >> 1, wp = w & 1;
  const int o0 = wo << 5;
  const int pbase = (blockIdx.x << 7) + (wp << 6);

  f32x4 acc[2][4];
#pragma unroll
  for (int ot = 0; ot < 2; ++ot) {
    float4 bv = *(const float4*)(bias + o0 + (ot << 4) + (g << 2));
    if (z == 0) { bv.x *= LOG2E; bv.y *= LOG2E; bv.z *= LOG2E; bv.w *= LOG2E; }
#pragma unroll
    for (int pt = 0; pt < 4; ++pt) acc[ot][pt] = (f32x4){bv.x, bv.y, bv.z, bv.w};
  }

  const float* xb = qf + ((((b << 8) + (g << 3)) << 10) + pbase + l16);
  const bf16* whb = Wh + ((o0 + l16) << 8) + (g << 3);
  const bf16* wlb = Wl + ((o0 + l16) << 8) + (g << 3);

  for (int kk = 0; kk < 8; ++kk) {
    bf16x8 ah[2], al[2];
#pragma unroll
    for (int ot = 0; ot < 2; ++ot) {
      ah[ot] = *(const bf16x8*)(whb + (ot << 12) + (kk << 5));
      al[ot] = *(const bf16x8*)(wlb + (ot << 12) + (kk << 5));
    }
#pragma unroll
    for (int pt = 0; pt < 4; ++pt) {
      bf16x8 xf;
      if (z == 0) {
        const float* xk = xb + (kk << 15);
        float xv[8];
#pragma unroll
        for (int j = 0; j < 8; ++j) xv[j] = xk[(j << 10) + (pt << 4)];
#pragma unroll
        for (int j = 0; j < 8; ++j) xf[j] = (bf16)xv[j];
      } else {
        // c = kk*32+8g+j ; p = pbase+16pt+l16 ; kt = p>>7, q'=p&127
        const int p = pbase + (pt << 4) + l16;
        const int mm = (p & 127) >> 3, e = p & 7;
        const char* vp = (const char*)KV + (size_t)((b << 3) + (p >> 7)) * 81920 +
                         16384 + ((kk >> 1) << 14) + ((mm >> 2) << 12) +
                         ((((kk & 1) << 1) + (g >> 1)) << 10) + ((mm & 3) << 8) +
                         (((g & 1) << 3) << 4) + (e << 1);
#pragma unroll
        for (int j = 0; j < 8; ++j)
          xf[j] = *(const bf16*)(vp + (j << 4));
      }
#pragma unroll
      for (int ot = 0; ot < 2; ++ot) {
        acc[ot][pt] = MFMA16(ah[ot], xf, acc[ot][pt]);
        acc[ot][pt] = MFMA16(al[ot], xf, acc[ot][pt]);
      }
    }
  }

#pragma unroll
  for (int ot = 0; ot < 2; ++ot)
#pragma unroll
    for (int pt = 0; pt < 4; ++pt) {
      bf16x4 q4;
#pragma unroll
      for (int r = 0; r < 4; ++r) q4[r] = (bf16)acc[ot][pt][r];
      int p = pbase + (pt << 4) + l16;
      if (z == 0) {
        *(bf16x4*)(Qp + ((((b << 10) + p)) << 6) + o0 + (ot << 4) + (g << 2)) = q4;
      } else {
        // K fragment-pack: q -> (qt, kl16); o = 32wo+16ot+4g+r
        int kt = p >> 7, q = p & 127;
        int qt = (q & 1) | ((q >> 5) << 1);
        int kl16 = (((q >> 3) & 3) << 2) | ((q >> 1) & 3);
        char* dst = (char*)KV + (size_t)((b << 3) + kt) * 81920 + (qt << 11) +
                    (wo << 10) + (((ot << 1) + (g >> 1)) << 8) + (kl16 << 4) +
                    ((g & 1) << 3);
        *(bf16x4*)dst = q4;
      }
    }
}

// ---------------------------------------------------------------------------
// Kernel 3: fused flash attention — NO K LDS. grid 512 (XCD-swz) x 256 thr,
// 4 blocks/CU. KVBLK=128, 8 iters, no-max exp2 softmax. K A-frags loaded
// direct from fragment-packed global (1KB coalesced wave-reads, identical
// addrs across the 4 waves -> L1-shared). V frags global->VGPR inside PV
// groups. Only LDS: sP double-buffer (P sharing) -> ONE barrier/iter
// (R14 safety chain). launch_bounds(256,4) for 16 waves/CU.
// ---------------------------------------------------------------------------
__global__ __launch_bounds__(256, 4) void attn_kernel(const bf16* __restrict__ KV,
                                                      const bf16* __restrict__ Qp,
                                                      float* __restrict__ out) {
  const int bid = blockIdx.x;
  const int wkid = ((bid & 7) << 6) + (bid >> 3);  // bijective: 512 % 8 == 0
  const int b = wkid >> 4, ptile = wkid & 15;
  const int p0 = ptile << 6;
  const int t = threadIdx.x;
  const int w = t >> 6, lane = t & 63;
  const int u = lane >> 4, l16 = lane & 15;

  __shared__ __align__(16) unsigned char sP[2][16384];  // P dbuf [64px][128kv]
  __shared__ float sL[64];

  // Q B-fragments for this wave's 16 px (col=px, k=o)
  const bf16* qb = Qp + (((size_t)((b << 10) + p0 + (w << 4) + l16)) << 6) + (u << 3);
  const bf16x8 qa0 = *(const bf16x8*)qb;
  const bf16x8 qa1 = *(const bf16x8*)(qb + 32);

  const char* chunk0 = (const char*)KV + (size_t)b * (8 * 81920);

  f32x4 acc[4][4];  // [pg][ct]: c = 64w + 16ct + 4u + r ; px = 16pg + l16
#pragma unroll
  for (int i = 0; i < 4; ++i)
#pragma unroll
    for (int j = 0; j < 4; ++j) acc[i][j] = (f32x4){0.f, 0.f, 0.f, 0.f};
  float l_ = 0.f;

  const int prow = (w << 4) + l16, pswz = prow & 7;

  for (int kt = 0; kt < 8; ++kt) {
    const int cur = kt & 1;
    const char* kbase = chunk0 + kt * 81920 + (lane << 4);

    // ---- S^T = K·Q^T: K A-frags direct from packed global (L1-shared).
    //      Two half-groups of 8 loads each to bound register pressure. ----
    f32x4 s[8];
#pragma unroll
    for (int h = 0; h < 2; ++h) {
      bf16x8 kr0[4], kr1[4];
#pragma unroll
      for (int q4i = 0; q4i < 4; ++q4i) {
        const char* kq = kbase + (((h << 2) + q4i) << 11);
        kr0[q4i] = *(const bf16x8*)kq;
        kr1[q4i] = *(const bf16x8*)(kq + 1024);
      }
#pragma unroll
      for (int q4i = 0; q4i < 4; ++q4i) {
        f32x4 z = (f32x4){0.f, 0.f, 0.f, 0.f};
        z = MFMA16(kr0[q4i], qa0, z);
        s[(h << 2) + q4i] = MFMA16(kr1[q4i], qa1, z);
      }
    }
    // ---- NO-MAX softmax: P = exp2(S); l += sum ----
#pragma unroll
    for (int qt = 0; qt < 8; ++qt)
#pragma unroll
      for (int r = 0; r < 4; ++r) s[qt][r] = exp2f(s[qt][r]);
    float rs = 0.f;
#pragma unroll
    for (int qt = 0; qt < 8; ++qt)
      rs += (s[qt][0] + s[qt][1]) + (s[qt][2] + s[qt][3]);
    rs += __shfl_xor(rs, 16);
    rs += __shfl_xor(rs, 32);
    l_ += rs;
    // ---- P -> bf16 octets (in-lane), publish 4 b128 into sP[cur] ----
#pragma unroll
    for (int a = 0; a < 4; ++a) {
      bf16x8 pb;
#pragma unroll
      for (int r = 0; r < 4; ++r) {
        pb[2 * r] = (bf16)s[2 * a][r];
        pb[2 * r + 1] = (bf16)s[2 * a + 1][r];
      }
      *(bf16x8*)(sP[cur] + prow * 256 + 16 * (((a << 2) + u) ^ pswz)) = pb;
    }
    __syncthreads();  // SINGLE barrier: P(t) visible; prior-iter hazards
                      // covered by barrier chain (see R14 argument)

    // ---- PV: 4 kb-groups x [4 P-frag + 4 V-frag loads + 16 mfma] ----
    const char* vsrc = chunk0 + kt * 81920 + 16384 + (w << 14) + (lane << 4);
#pragma unroll
    for (int kb = 0; kb < 4; ++kb) {
      bf16x8 vr4[4];
#pragma unroll
      for (int ct = 0; ct < 4; ++ct)
        vr4[ct] = *(const bf16x8*)(vsrc + (((kb << 2) + ct) << 10));
      bf16x8 pbr[4];
#pragma unroll
      for (int pg = 0; pg < 4; ++pg) {
        const int rr = (pg << 4) + l16;
        pbr[pg] = *(const bf16x8*)(sP[cur] + rr * 256 + 16 * (((kb << 2) + u) ^ (rr & 7)));
      }
#pragma unroll
      for (int ct = 0; ct < 4; ++ct)
#pragma unroll
        for (int pg = 0; pg < 4; ++pg)
          acc[pg][ct] = MFMA16(vr4[ct], pbr[pg], acc[pg][ct]);
    }
  }

  // ---- epilogue: share l, per-lane normalize, direct stores ----
  __syncthreads();
  if (lane < 16) sL[(w << 4) + lane] = l_;
  __syncthreads();
#pragma unroll
  for (int pg = 0; pg < 4; ++pg) {
    const float inv = 1.f / sL[(pg << 4) + l16];
    float* ob = out + ((size_t)b << 18) + p0 + (pg << 4) + l16;
#pragma unroll
    for (int ct = 0; ct < 4; ++ct)
#pragma unroll
      for (int r = 0; r < 4; ++r) {
        int c = (w << 6) + (ct << 4) + (u << 2) + r;
        ob[(size_t)c << 10] = acc[pg][ct][r] * inv;
      }
  }
}

// ---------------------------------------------------------------------------
extern "C" void kernel_launch(void* const* d_in, const int* in_sizes, int n_in,
                              void* d_out, int out_size, void* d_ws, size_t ws_size,
                              hipStream_t stream) {
  const float* qf = (const float*)d_in[0];
  const float* kf = (const float*)d_in[1];
  const float* Wq = (const float*)d_in[2];
  const float* bq = (const float*)d_in[3];
  const float* Wk = (const float*)d_in[4];
  const float* bk = (const float*)d_in[5];
  // d_in[6] = vis_CA (unused)
  const int* flag = (const int*)d_in[7];  // same_WqWk
  float* out = (float*)d_out;

  char* ws = (char*)d_ws;
  bf16* Qp = (bf16*)ws;                          // 4 MiB: [32][1024][64] bf16
  bf16* Wbh = (bf16*)(ws + (4u << 20));          // 64 KiB
  bf16* Wbl = (bf16*)(ws + (4u << 20) + 65536);  // 64 KiB
  bf16* KV = (bf16*)(ws + (5u << 20));           // 20 MiB: [32][8] x 81920B chunks

  vprep_kernel<<<4128, 256, 0, stream>>>(kf, Wq, Wk, flag, KV, Wbh, Wbl);
  proj_kernel<<<dim3(8, 32, 2), 256, 0, stream>>>(qf, Wbh, Wbl, bq, bk, flag, Qp, KV);
  attn_kernel<<<512, 256, 0, stream>>>(KV, Qp, out);
}

// Round 17
// 81.861 us; speedup vs baseline: 1.0977x; 1.0977x over previous
//
#include <hip/hip_runtime.h>

typedef __bf16 bf16;
typedef __attribute__((ext_vector_type(4))) __bf16 bf16x4;
typedef __attribute__((ext_vector_type(8))) __bf16 bf16x8;
typedef __attribute__((ext_vector_type(4))) float f32x4;
typedef unsigned int u32;

#define MFMA16(a, b, c) __builtin_amdgcn_mfma_f32_16x16x32_bf16((a), (b), (c), 0, 0, 0)
#define LOG2E 1.4426950408889634f

// KV chunk, per (b, kt=0..7): 81920 bytes =
//  [0,16384): K packed in FRAGMENT order: for mfma qt (0..7), half h (0..1),
//     lane L=(u<<4)|l16, elem j: byte = qt<<11 | h<<10 | L<<4 | j<<1 holds
//     K[row R(qt,l16)][o=32h+8u+j] — attn lane L loading qt<<11 (+1024) +
//     L<<4 gets its S A-frag directly (L1-shared across the 4 waves).
//  [16384,81920): V packed for direct wave-frag loads (R12): octet (c, mm)
//     at 16384 + (c>>6)<<14 + (mm>>2)<<12 + ((c>>4)&3)<<10 + (mm&3)<<8 +
//     (c&15)<<4. Wave w: load k at (w<<14)+(k<<10)+(lane<<4) == A-frag
//     (c=64w+16ct+l16, octet mm=4kb+u), k=4kb+ct.

// ---------------------------------------------------------------------------
// Kernel 1: fused V-pack + W prep (R12 verbatim).
// ---------------------------------------------------------------------------
__global__ __launch_bounds__(256) void vprep_kernel(const float* __restrict__ kf,
                                                    const float* __restrict__ Wq,
                                                    const float* __restrict__ Wk,
                                                    const int* __restrict__ flag,
                                                    bf16* __restrict__ KV,
                                                    bf16* __restrict__ Wbh,
                                                    bf16* __restrict__ Wbl) {
  const int bid = blockIdx.x, t = threadIdx.x;
  if (bid < 4096) {
    int i = (bid << 8) + t;  // (b, c, q8)
    int q8 = i & 127, c = (i >> 7) & 255, b = i >> 15;
    const float* src = kf + ((size_t)(((b << 8) + c)) << 10) + (q8 << 3);
    float4 f0 = *(const float4*)src;
    float4 f1 = *(const float4*)(src + 4);
    bf16x8 v;
    v[0] = (bf16)f0.x; v[1] = (bf16)f0.y; v[2] = (bf16)f0.z; v[3] = (bf16)f0.w;
    v[4] = (bf16)f1.x; v[5] = (bf16)f1.y; v[6] = (bf16)f1.z; v[7] = (bf16)f1.w;
    int kt = q8 >> 4, mm = q8 & 15;
    char* dst = (char*)KV + (size_t)((b << 3) + kt) * 81920 + 16384 +
                ((c >> 6) << 14) + ((mm >> 2) << 12) + (((c >> 4) & 3) << 10) +
                ((mm & 3) << 8) + ((c & 15) << 4);
    *(bf16x8*)dst = v;
  } else {
    int bx = bid - 4096;  // 0..31
    int z = bx >> 4;
    const float* src = (z == 0) ? Wq : ((flag[0] != 0) ? Wq : Wk);
    const float sc = (z == 0) ? LOG2E : 1.0f;  // exp2-domain softmax
    int i = ((((bx & 15) << 8) + t) << 2);
    float4 vv = *(const float4*)(src + i);
    vv.x *= sc; vv.y *= sc; vv.z *= sc; vv.w *= sc;
    bf16x4 hi, lo;
    hi[0] = (bf16)vv.x; lo[0] = (bf16)(vv.x - (float)hi[0]);
    hi[1] = (bf16)vv.y; lo[1] = (bf16)(vv.y - (float)hi[1]);
    hi[2] = (bf16)vv.z; lo[2] = (bf16)(vv.z - (float)hi[2]);
    hi[3] = (bf16)vv.w; lo[3] = (bf16)(vv.w - (float)hi[3]);
    *(bf16x4*)(Wbh + (z << 14) + i) = hi;
    *(bf16x4*)(Wbl + (z << 14) + i) = lo;
  }
}

// ---------------------------------------------------------------------------
// Kernel 2: MFMA projection (R15 verbatim). z=0 -> Qp (log2e-scaled);
// z=1 -> KV K-part in FRAGMENT-packed order; B-frags from packed KV V-region.
// ---------------------------------------------------------------------------
__global__ __launch_bounds__(256) void proj_kernel(const float* __restrict__ qf,
                                                   const bf16* __restrict__ Wbh,
                                                   const bf16* __restrict__ Wbl,
                                                   const float* __restrict__ bq,
                                                   const float* __restrict__ bk,
                                                   const int* __restrict__ flag,
                                                   bf16* __restrict__ Qp,
                                                   bf16* __restrict__ KV) {
  const int b = blockIdx.y, z = blockIdx.z;
  const bf16* Wh = Wbh + z * 16384;
  const bf16* Wl = Wbl + z * 16384;
  const float* bias = z ? (flag[0] ? bq : bk) : bq;

  const int t = threadIdx.x;
  const int w = t >> 6, lane = t & 63;
  const int g = lane >> 4, l16 = lane & 15;
  const int wo = w >> 1, wp = w & 1;
  const int o0 = wo << 5;
  const int pbase = (blockIdx.x << 7) + (wp << 6);

  f32x4 acc[2][4];
#pragma unroll
  for (int ot = 0; ot < 2; ++ot) {
    float4 bv = *(const float4*)(bias + o0 + (ot << 4) + (g << 2));
    if (z == 0) { bv.x *= LOG2E; bv.y *= LOG2E; bv.z *= LOG2E; bv.w *= LOG2E; }
#pragma unroll
    for (int pt = 0; pt < 4; ++pt) acc[ot][pt] = (f32x4){bv.x, bv.y, bv.z, bv.w};
  }

  const float* xb = qf + ((((b << 8) + (g << 3)) << 10) + pbase + l16);
  const bf16* whb = Wh + ((o0 + l16) << 8) + (g << 3);
  const bf16* wlb = Wl + ((o0 + l16) << 8) + (g << 3);

  for (int kk = 0; kk < 8; ++kk) {
    bf16x8 ah[2], al[2];
#pragma unroll
    for (int ot = 0; ot < 2; ++ot) {
      ah[ot] = *(const bf16x8*)(whb + (ot << 12) + (kk << 5));
      al[ot] = *(const bf16x8*)(wlb + (ot << 12) + (kk << 5));
    }
#pragma unroll
    for (int pt = 0; pt < 4; ++pt) {
      bf16x8 xf;
      if (z == 0) {
        const float* xk = xb + (kk << 15);
        float xv[8];
#pragma unroll
        for (int j = 0; j < 8; ++j) xv[j] = xk[(j << 10) + (pt << 4)];
#pragma unroll
        for (int j = 0; j < 8; ++j) xf[j] = (bf16)xv[j];
      } else {
        // c = kk*32+8g+j ; p = pbase+16pt+l16 ; kt = p>>7, q'=p&127
        const int p = pbase + (pt << 4) + l16;
        const int mm = (p & 127) >> 3, e = p & 7;
        const char* vp = (const char*)KV + (size_t)((b << 3) + (p >> 7)) * 81920 +
                         16384 + ((kk >> 1) << 14) + ((mm >> 2) << 12) +
                         ((((kk & 1) << 1) + (g >> 1)) << 10) + ((mm & 3) << 8) +
                         (((g & 1) << 3) << 4) + (e << 1);
#pragma unroll
        for (int j = 0; j < 8; ++j)
          xf[j] = *(const bf16*)(vp + (j << 4));
      }
#pragma unroll
      for (int ot = 0; ot < 2; ++ot) {
        acc[ot][pt] = MFMA16(ah[ot], xf, acc[ot][pt]);
        acc[ot][pt] = MFMA16(al[ot], xf, acc[ot][pt]);
      }
    }
  }

#pragma unroll
  for (int ot = 0; ot < 2; ++ot)
#pragma unroll
    for (int pt = 0; pt < 4; ++pt) {
      bf16x4 q4;
#pragma unroll
      for (int r = 0; r < 4; ++r) q4[r] = (bf16)acc[ot][pt][r];
      int p = pbase + (pt << 4) + l16;
      if (z == 0) {
        *(bf16x4*)(Qp + ((((b << 10) + p)) << 6) + o0 + (ot << 4) + (g << 2)) = q4;
      } else {
        // K fragment-pack: q -> (qt, kl16); o = 32wo+16ot+4g+r
        int kt = p >> 7, q = p & 127;
        int qt = (q & 1) | ((q >> 5) << 1);
        int kl16 = (((q >> 3) & 3) << 2) | ((q >> 1) & 3);
        char* dst = (char*)KV + (size_t)((b << 3) + kt) * 81920 + (qt << 11) +
                    (wo << 10) + (((ot << 1) + (g >> 1)) << 8) + (kl16 << 4) +
                    ((g & 1) << 3);
        *(bf16x4*)dst = q4;
      }
    }
}

// ---------------------------------------------------------------------------
// Kernel 3: fused flash attention — NO K LDS (R15 structure), launch_bounds
// min-waves FIXED 4 -> 3 so the allocator gets ~168 VGPRs (R15's cap of 64
// caused ~39 MB of scratch spills; body needs ~120). 3-4 blocks/CU via
// LDS=33 KB. One barrier/iter; K/V direct from fragment-packed global.
// ---------------------------------------------------------------------------
__global__ __launch_bounds__(256, 3) void attn_kernel(const bf16* __restrict__ KV,
                                                      const bf16* __restrict__ Qp,
                                                      float* __restrict__ out) {
  const int bid = blockIdx.x;
  const int wkid = ((bid & 7) << 6) + (bid >> 3);  // bijective: 512 % 8 == 0
  const int b = wkid >> 4, ptile = wkid & 15;
  const int p0 = ptile << 6;
  const int t = threadIdx.x;
  const int w = t >> 6, lane = t & 63;
  const int u = lane >> 4, l16 = lane & 15;

  __shared__ __align__(16) unsigned char sP[2][16384];  // P dbuf [64px][128kv]
  __shared__ float sL[64];

  // Q B-fragments for this wave's 16 px (col=px, k=o)
  const bf16* qb = Qp + (((size_t)((b << 10) + p0 + (w << 4) + l16)) << 6) + (u << 3);
  const bf16x8 qa0 = *(const bf16x8*)qb;
  const bf16x8 qa1 = *(const bf16x8*)(qb + 32);

  const char* chunk0 = (const char*)KV + (size_t)b * (8 * 81920);

  f32x4 acc[4][4];  // [pg][ct]: c = 64w + 16ct + 4u + r ; px = 16pg + l16
#pragma unroll
  for (int i = 0; i < 4; ++i)
#pragma unroll
    for (int j = 0; j < 4; ++j) acc[i][j] = (f32x4){0.f, 0.f, 0.f, 0.f};
  float l_ = 0.f;

  const int prow = (w << 4) + l16, pswz = prow & 7;

  for (int kt = 0; kt < 8; ++kt) {
    const int cur = kt & 1;
    const char* kbase = chunk0 + kt * 81920 + (lane << 4);

    // ---- S^T = K·Q^T: K A-frags direct from packed global (L1-shared).
    //      Two half-groups of 8 loads each to bound register pressure. ----
    f32x4 s[8];
#pragma unroll
    for (int h = 0; h < 2; ++h) {
      bf16x8 kr0[4], kr1[4];
#pragma unroll
      for (int q4i = 0; q4i < 4; ++q4i) {
        const char* kq = kbase + (((h << 2) + q4i) << 11);
        kr0[q4i] = *(const bf16x8*)kq;
        kr1[q4i] = *(const bf16x8*)(kq + 1024);
      }
#pragma unroll
      for (int q4i = 0; q4i < 4; ++q4i) {
        f32x4 z = (f32x4){0.f, 0.f, 0.f, 0.f};
        z = MFMA16(kr0[q4i], qa0, z);
        s[(h << 2) + q4i] = MFMA16(kr1[q4i], qa1, z);
      }
    }
    // ---- NO-MAX softmax: P = exp2(S); l += sum ----
#pragma unroll
    for (int qt = 0; qt < 8; ++qt)
#pragma unroll
      for (int r = 0; r < 4; ++r) s[qt][r] = exp2f(s[qt][r]);
    float rs = 0.f;
#pragma unroll
    for (int qt = 0; qt < 8; ++qt)
      rs += (s[qt][0] + s[qt][1]) + (s[qt][2] + s[qt][3]);
    rs += __shfl_xor(rs, 16);
    rs += __shfl_xor(rs, 32);
    l_ += rs;
    // ---- P -> bf16 octets (in-lane), publish 4 b128 into sP[cur] ----
#pragma unroll
    for (int a = 0; a < 4; ++a) {
      bf16x8 pb;
#pragma unroll
      for (int r = 0; r < 4; ++r) {
        pb[2 * r] = (bf16)s[2 * a][r];
        pb[2 * r + 1] = (bf16)s[2 * a + 1][r];
      }
      *(bf16x8*)(sP[cur] + prow * 256 + 16 * (((a << 2) + u) ^ pswz)) = pb;
    }
    __syncthreads();  // SINGLE barrier: P(t) visible; prior-iter hazards
                      // covered by the barrier chain (R14 argument)

    // ---- PV: 4 kb-groups x [4 P-frag + 4 V-frag loads + 16 mfma] ----
    const char* vsrc = chunk0 + kt * 81920 + 16384 + (w << 14) + (lane << 4);
#pragma unroll
    for (int kb = 0; kb < 4; ++kb) {
      bf16x8 vr4[4];
#pragma unroll
      for (int ct = 0; ct < 4; ++ct)
        vr4[ct] = *(const bf16x8*)(vsrc + (((kb << 2) + ct) << 10));
      bf16x8 pbr[4];
#pragma unroll
      for (int pg = 0; pg < 4; ++pg) {
        const int rr = (pg << 4) + l16;
        pbr[pg] = *(const bf16x8*)(sP[cur] + rr * 256 + 16 * (((kb << 2) + u) ^ (rr & 7)));
      }
#pragma unroll
      for (int ct = 0; ct < 4; ++ct)
#pragma unroll
        for (int pg = 0; pg < 4; ++pg)
          acc[pg][ct] = MFMA16(vr4[ct], pbr[pg], acc[pg][ct]);
    }
  }

  // ---- epilogue: share l, per-lane normalize, direct stores ----
  __syncthreads();
  if (lane < 16) sL[(w << 4) + lane] = l_;
  __syncthreads();
#pragma unroll
  for (int pg = 0; pg < 4; ++pg) {
    const float inv = 1.f / sL[(pg << 4) + l16];
    float* ob = out + ((size_t)b << 18) + p0 + (pg << 4) + l16;
#pragma unroll
    for (int ct = 0; ct < 4; ++ct)
#pragma unroll
      for (int r = 0; r < 4; ++r) {
        int c = (w << 6) + (ct << 4) + (u << 2) + r;
        ob[(size_t)c << 10] = acc[pg][ct][r] * inv;
      }
  }
}

// ---------------------------------------------------------------------------
extern "C" void kernel_launch(void* const* d_in, const int* in_sizes, int n_in,
                              void* d_out, int out_size, void* d_ws, size_t ws_size,
                              hipStream_t stream) {
  const float* qf = (const float*)d_in[0];
  const float* kf = (const float*)d_in[1];
  const float* Wq = (const float*)d_in[2];
  const float* bq = (const float*)d_in[3];
  const float* Wk = (const float*)d_in[4];
  const float* bk = (const float*)d_in[5];
  // d_in[6] = vis_CA (unused)
  const int* flag = (const int*)d_in[7];  // same_WqWk
  float* out = (float*)d_out;

  char* ws = (char*)d_ws;
  bf16* Qp = (bf16*)ws;                          // 4 MiB: [32][1024][64] bf16
  bf16* Wbh = (bf16*)(ws + (4u << 20));          // 64 KiB
  bf16* Wbl = (bf16*)(ws + (4u << 20) + 65536);  // 64 KiB
  bf16* KV = (bf16*)(ws + (5u << 20));           // 20 MiB: [32][8] x 81920B chunks

  vprep_kernel<<<4128, 256, 0, stream>>>(kf, Wq, Wk, flag, KV, Wbh, Wbl);
  proj_kernel<<<dim3(8, 32, 2), 256, 0, stream>>>(qf, Wbh, Wbl, bq, bk, flag, Qp, KV);
  attn_kernel<<<512, 256, 0, stream>>>(KV, Qp, out);
}